// Round 1
// baseline (196.062 us; speedup 1.0000x reference)
//
#include <hip/hip_runtime.h>

namespace {
constexpr float GRAVITY     = 10.0f;
constexpr float MAIN_THRUST = 6.0f;
constexpr float DT          = 0.02f;
}

// One thread per batch element. Memory-bound: 356 B/thread of HBM traffic.
// F is sparse (identity + 8 nonzeros) -> F*P*F^T done as two 2-FMA/entry passes.
// 3x3 solve via adjugate (S is SPD-ish, cond ~O(1)). Joseph form matches ref.
__global__ __launch_bounds__(256) void ekf_kernel(
    const float* __restrict__ z,           // (B,3)
    const float* __restrict__ u,           // (B,2)
    const float* __restrict__ x_prev,      // (B,6)
    const float* __restrict__ P_prev,      // (B,36)
    const float* __restrict__ q_log_diag,  // (6,)
    const float* __restrict__ q_off_diag,  // (15,)
    const float* __restrict__ r_log_diag,  // (3,)
    const float* __restrict__ r_off_diag,  // (3,)
    float* __restrict__ x_out,             // (B,6)
    float* __restrict__ P_out,             // (B,36)
    int B)
{
    const int b = blockIdx.x * blockDim.x + threadIdx.x;
    if (b >= B) return;

    // ---------- uniform Q (6x6) = L L^T + 1e-6 I ----------
    // np.tril_indices(6,-1) row-major: (1,0)(2,0)(2,1)(3,0)(3,1)(3,2)
    //                                  (4,0..3)(5,0..4)
    float L[6][6];
    #pragma unroll
    for (int i = 0; i < 6; ++i)
        #pragma unroll
        for (int j = 0; j < 6; ++j) L[i][j] = 0.0f;
    #pragma unroll
    for (int i = 0; i < 6; ++i) L[i][i] = expf(q_log_diag[i]);
    L[1][0] = q_off_diag[0];
    L[2][0] = q_off_diag[1];  L[2][1] = q_off_diag[2];
    L[3][0] = q_off_diag[3];  L[3][1] = q_off_diag[4];  L[3][2] = q_off_diag[5];
    L[4][0] = q_off_diag[6];  L[4][1] = q_off_diag[7];  L[4][2] = q_off_diag[8];
    L[4][3] = q_off_diag[9];
    L[5][0] = q_off_diag[10]; L[5][1] = q_off_diag[11]; L[5][2] = q_off_diag[12];
    L[5][3] = q_off_diag[13]; L[5][4] = q_off_diag[14];

    float Q[6][6];
    #pragma unroll
    for (int i = 0; i < 6; ++i) {
        #pragma unroll
        for (int j = 0; j <= i; ++j) {
            float s = 0.0f;
            #pragma unroll
            for (int k = 0; k <= j; ++k) s += L[i][k] * L[j][k];
            if (i == j) s += 1e-6f;
            Q[i][j] = s;
            Q[j][i] = s;
        }
    }

    // ---------- uniform R (3x3) = Lr Lr^T + 1e-6 I ----------
    // np.tril_indices(3,-1): (1,0)(2,0)(2,1)
    float rd0 = expf(r_log_diag[0]);
    float rd1 = expf(r_log_diag[1]);
    float rd2 = expf(r_log_diag[2]);
    float ro0 = r_off_diag[0], ro1 = r_off_diag[1], ro2 = r_off_diag[2];
    float R00 = rd0 * rd0 + 1e-6f;
    float R10 = ro0 * rd0;
    float R11 = ro0 * ro0 + rd1 * rd1 + 1e-6f;
    float R20 = ro1 * rd0;
    float R21 = ro1 * ro0 + ro2 * rd1;
    float R22 = ro1 * ro1 + ro2 * ro2 + rd2 * rd2 + 1e-6f;
    float Rm[3][3] = {{R00, R10, R20}, {R10, R11, R21}, {R20, R21, R22}};

    // ---------- load state / control / measurement ----------
    const float2* xp2 = reinterpret_cast<const float2*>(x_prev + 6 * b);
    float2 x01 = xp2[0], x23 = xp2[1], x45 = xp2[2];
    const float px = x01.x, py = x01.y, vx = x23.x, vy = x23.y;
    const float th = x45.x, om = x45.y;

    const float2 uu = *reinterpret_cast<const float2*>(u + 2 * b);
    const float mp  = fminf(fmaxf(uu.x, 0.0f), 1.0f);
    const float lat = uu.y;

    float s_th, c_th;
    __sincosf(th, &s_th, &c_th);

    // ---------- dynamics (x_pred) ----------
    const float Tm  = MAIN_THRUST * mp;
    const float ax  = -Tm * s_th;
    const float ay  =  Tm * c_th - GRAVITY;
    const float nvx = vx + ax * DT;
    const float nvy = vy + ay * DT;
    const float nom = om + lat * DT;          // SIDE_TORQUE = 1
    const float npx = px + nvx * DT;
    const float npy = py + nvy * DT;
    const float nth = th + nom * DT;
    float xp[6] = {npx, npy, nvx, nvy, nth, nom};

    // ---------- Jacobian nonzeros ----------
    const float f24 = -Tm * c_th * DT;        // F[2][4]
    const float f34 = -Tm * s_th * DT;        // F[3][4]
    const float f04 = f24 * DT;               // F[0][4]
    const float f14 = f34 * DT;               // F[1][4]

    // ---------- load P_prev (9 x float4, 144B contiguous) ----------
    float P[36];
    const float4* Pp4 = reinterpret_cast<const float4*>(P_prev + 36 * b);
    #pragma unroll
    for (int i = 0; i < 9; ++i) {
        float4 v = Pp4[i];
        P[4 * i + 0] = v.x; P[4 * i + 1] = v.y;
        P[4 * i + 2] = v.z; P[4 * i + 3] = v.w;
    }

    // ---------- P_pred = F P F^T + Q, in place ----------
    // Row pass (M = F P): rows in order 0..5; row i only reads rows >= i.
    #pragma unroll
    for (int j = 0; j < 6; ++j) {
        P[0 * 6 + j] += DT * P[2 * 6 + j] + f04 * P[4 * 6 + j];
        P[1 * 6 + j] += DT * P[3 * 6 + j] + f14 * P[4 * 6 + j];
        P[2 * 6 + j] += f24 * P[4 * 6 + j];
        P[3 * 6 + j] += f34 * P[4 * 6 + j];
        P[4 * 6 + j] += DT * P[5 * 6 + j];
    }
    // Column pass (P_pred = M F^T) + Q, per row with saved olds.
    #pragma unroll
    for (int i = 0; i < 6; ++i) {
        const float m0 = P[i * 6 + 0], m1 = P[i * 6 + 1], m2 = P[i * 6 + 2];
        const float m3 = P[i * 6 + 3], m4 = P[i * 6 + 4], m5 = P[i * 6 + 5];
        P[i * 6 + 0] = m0 + DT * m2 + f04 * m4 + Q[i][0];
        P[i * 6 + 1] = m1 + DT * m3 + f14 * m4 + Q[i][1];
        P[i * 6 + 2] = m2 + f24 * m4 + Q[i][2];
        P[i * 6 + 3] = m3 + f34 * m4 + Q[i][3];
        P[i * 6 + 4] = m4 + DT * m5 + Q[i][4];
        P[i * 6 + 5] = m5 + Q[i][5];
    }

    // ---------- innovation ----------
    const float* zp = z + 3 * b;
    const float y0 = zp[0] - npx;
    const float y1 = zp[1] - npy;
    const float y2 = zp[2] - nth;

    // ---------- S = P_pred[h,h] + R, h = {0,1,4}; invert (adjugate) ----------
    const float s00 = P[0 * 6 + 0] + Rm[0][0];
    const float s01 = P[0 * 6 + 1] + Rm[0][1];
    const float s02 = P[0 * 6 + 4] + Rm[0][2];
    const float s10 = P[1 * 6 + 0] + Rm[1][0];
    const float s11 = P[1 * 6 + 1] + Rm[1][1];
    const float s12 = P[1 * 6 + 4] + Rm[1][2];
    const float s20 = P[4 * 6 + 0] + Rm[2][0];
    const float s21 = P[4 * 6 + 1] + Rm[2][1];
    const float s22 = P[4 * 6 + 4] + Rm[2][2];

    const float det = s00 * (s11 * s22 - s12 * s21)
                    + s01 * (s12 * s20 - s10 * s22)
                    + s02 * (s10 * s21 - s11 * s20);
    const float invd = 1.0f / det;
    const float i00 = (s11 * s22 - s12 * s21) * invd;
    const float i01 = (s02 * s21 - s01 * s22) * invd;
    const float i02 = (s01 * s12 - s02 * s11) * invd;
    const float i10 = (s12 * s20 - s10 * s22) * invd;
    const float i11 = (s00 * s22 - s02 * s20) * invd;
    const float i12 = (s02 * s10 - s00 * s12) * invd;
    const float i20 = (s10 * s21 - s11 * s20) * invd;
    const float i21 = (s01 * s20 - s00 * s21) * invd;
    const float i22 = (s00 * s11 - s01 * s10) * invd;

    // ---------- K = HP^T S^{-1}  (6x3); HP[a][i] = P_pred[h_a*6 + i] ----------
    float K[6][3];
    #pragma unroll
    for (int i = 0; i < 6; ++i) {
        const float hp0 = P[0 * 6 + i];
        const float hp1 = P[1 * 6 + i];
        const float hp2 = P[4 * 6 + i];
        K[i][0] = i00 * hp0 + i01 * hp1 + i02 * hp2;
        K[i][1] = i10 * hp0 + i11 * hp1 + i12 * hp2;
        K[i][2] = i20 * hp0 + i21 * hp1 + i22 * hp2;
    }

    // ---------- x_upd = x_pred + K y; store early ----------
    float2* xo2 = reinterpret_cast<float2*>(x_out + 6 * b);
    float xu[6];
    #pragma unroll
    for (int i = 0; i < 6; ++i)
        xu[i] = xp[i] + K[i][0] * y0 + K[i][1] * y1 + K[i][2] * y2;
    xo2[0] = make_float2(xu[0], xu[1]);
    xo2[1] = make_float2(xu[2], xu[3]);
    xo2[2] = make_float2(xu[4], xu[5]);

    // ---------- Joseph form: P_upd = IKH P_pred IKH^T + K R K^T ----------
    // T = IKH * P_pred, in place (save rows 0,1,4 of P_pred first).
    float r0[6], r1[6], r4[6];
    #pragma unroll
    for (int j = 0; j < 6; ++j) {
        r0[j] = P[0 * 6 + j];
        r1[j] = P[1 * 6 + j];
        r4[j] = P[4 * 6 + j];
    }
    #pragma unroll
    for (int i = 0; i < 6; ++i)
        #pragma unroll
        for (int j = 0; j < 6; ++j)
            P[i * 6 + j] -= K[i][0] * r0[j] + K[i][1] * r1[j] + K[i][2] * r4[j];

    // P_upd = T * IKH^T + K R K^T, in place (save cols 0,1,4 of T first).
    float c0[6], c1[6], c4[6];
    #pragma unroll
    for (int i = 0; i < 6; ++i) {
        c0[i] = P[i * 6 + 0];
        c1[i] = P[i * 6 + 1];
        c4[i] = P[i * 6 + 4];
    }
    float KR[6][3];
    #pragma unroll
    for (int i = 0; i < 6; ++i) {
        #pragma unroll
        for (int a = 0; a < 3; ++a)
            KR[i][a] = K[i][0] * Rm[0][a] + K[i][1] * Rm[1][a] + K[i][2] * Rm[2][a];
    }
    #pragma unroll
    for (int i = 0; i < 6; ++i) {
        #pragma unroll
        for (int j = 0; j < 6; ++j) {
            P[i * 6 + j] += -(c0[i] * K[j][0] + c1[i] * K[j][1] + c4[i] * K[j][2])
                            + (KR[i][0] * K[j][0] + KR[i][1] * K[j][1] + KR[i][2] * K[j][2]);
        }
    }

    // ---------- store P_upd (9 x float4) ----------
    float4* Po4 = reinterpret_cast<float4*>(P_out + 36 * b);
    #pragma unroll
    for (int i = 0; i < 9; ++i) {
        float4 v;
        v.x = P[4 * i + 0]; v.y = P[4 * i + 1];
        v.z = P[4 * i + 2]; v.w = P[4 * i + 3];
        Po4[i] = v;
    }
}

extern "C" void kernel_launch(void* const* d_in, const int* in_sizes, int n_in,
                              void* d_out, int out_size, void* d_ws, size_t ws_size,
                              hipStream_t stream) {
    const float* z          = (const float*)d_in[0];
    const float* u          = (const float*)d_in[1];
    const float* x_prev     = (const float*)d_in[2];
    const float* P_prev     = (const float*)d_in[3];
    const float* q_log_diag = (const float*)d_in[4];
    const float* q_off_diag = (const float*)d_in[5];
    const float* r_log_diag = (const float*)d_in[6];
    const float* r_off_diag = (const float*)d_in[7];

    const int B = in_sizes[0] / 3;          // z is (B,3)
    float* x_out = (float*)d_out;           // (B,6)
    float* P_out = (float*)d_out + (size_t)B * 6;  // (B,36)

    const int block = 256;
    const int grid  = (B + block - 1) / block;
    ekf_kernel<<<grid, block, 0, stream>>>(z, u, x_prev, P_prev,
                                           q_log_diag, q_off_diag,
                                           r_log_diag, r_off_diag,
                                           x_out, P_out, B);
}

// Round 2
// 191.698 us; speedup vs baseline: 1.0228x; 1.0228x over previous
//
#include <hip/hip_runtime.h>

namespace {
constexpr float GRAVITY     = 10.0f;
constexpr float MAIN_THRUST = 6.0f;
constexpr float DT          = 0.02f;
constexpr int   BLK         = 256;
constexpr int   ROWPAD      = 37;   // 36 + 1: odd stride -> conflict-free LDS rows
}

// One thread per batch element, but P (144 B/elem) is staged through LDS so
// global loads/stores are block-linear float4 (fully coalesced). Thread t
// reads/writes only LDS row t, so just 2 barriers. F is sparse (identity + 8
// nonzeros); 3x3 solve via adjugate; Joseph form matches the reference.
__global__ __launch_bounds__(BLK) void ekf_kernel(
    const float* __restrict__ z,           // (B,3)
    const float* __restrict__ u,           // (B,2)
    const float* __restrict__ x_prev,      // (B,6)
    const float* __restrict__ P_prev,      // (B,36)
    const float* __restrict__ q_log_diag,  // (6,)
    const float* __restrict__ q_off_diag,  // (15,)
    const float* __restrict__ r_log_diag,  // (3,)
    const float* __restrict__ r_off_diag,  // (3,)
    float* __restrict__ x_out,             // (B,6)
    float* __restrict__ P_out,             // (B,36)
    int B)
{
    __shared__ float smem[BLK * ROWPAD];   // 37888 B -> 4 blocks/CU

    const int t = threadIdx.x;
    const long long blockElem0 = (long long)blockIdx.x * BLK;
    const long long elemsLeft  = (long long)B - blockElem0;
    const int nElem  = elemsLeft >= BLK ? BLK : (int)elemsLeft;  // full blocks: 256
    const int count4 = nElem * 9;                                 // float4s to stage

    // ---------- phase 1: coalesced global -> LDS (P_prev) ----------
    {
        const float4* gP4 = reinterpret_cast<const float4*>(P_prev + blockElem0 * 36);
        #pragma unroll
        for (int k = 0; k < 9; ++k) {
            const int g4 = t + k * BLK;
            if (g4 < count4) {
                const float4 v = gP4[g4];
                const int elem = g4 / 9;
                const int off4 = g4 % 9;
                float* dst = &smem[elem * ROWPAD + off4 * 4];
                dst[0] = v.x; dst[1] = v.y; dst[2] = v.z; dst[3] = v.w;
            }
        }
    }
    __syncthreads();

    const bool valid = (t < nElem);
    const long long b = blockElem0 + t;

    if (valid) {
        // ---------- uniform Q (6x6) = L L^T + 1e-6 I ----------
        float L[6][6];
        #pragma unroll
        for (int i = 0; i < 6; ++i)
            #pragma unroll
            for (int j = 0; j < 6; ++j) L[i][j] = 0.0f;
        #pragma unroll
        for (int i = 0; i < 6; ++i) L[i][i] = expf(q_log_diag[i]);
        L[1][0] = q_off_diag[0];
        L[2][0] = q_off_diag[1];  L[2][1] = q_off_diag[2];
        L[3][0] = q_off_diag[3];  L[3][1] = q_off_diag[4];  L[3][2] = q_off_diag[5];
        L[4][0] = q_off_diag[6];  L[4][1] = q_off_diag[7];  L[4][2] = q_off_diag[8];
        L[4][3] = q_off_diag[9];
        L[5][0] = q_off_diag[10]; L[5][1] = q_off_diag[11]; L[5][2] = q_off_diag[12];
        L[5][3] = q_off_diag[13]; L[5][4] = q_off_diag[14];

        float Q[6][6];
        #pragma unroll
        for (int i = 0; i < 6; ++i) {
            #pragma unroll
            for (int j = 0; j <= i; ++j) {
                float s = 0.0f;
                #pragma unroll
                for (int k = 0; k <= j; ++k) s += L[i][k] * L[j][k];
                if (i == j) s += 1e-6f;
                Q[i][j] = s;
                Q[j][i] = s;
            }
        }

        // ---------- uniform R (3x3) = Lr Lr^T + 1e-6 I ----------
        const float rd0 = expf(r_log_diag[0]);
        const float rd1 = expf(r_log_diag[1]);
        const float rd2 = expf(r_log_diag[2]);
        const float ro0 = r_off_diag[0], ro1 = r_off_diag[1], ro2 = r_off_diag[2];
        const float R00 = rd0 * rd0 + 1e-6f;
        const float R10 = ro0 * rd0;
        const float R11 = ro0 * ro0 + rd1 * rd1 + 1e-6f;
        const float R20 = ro1 * rd0;
        const float R21 = ro1 * ro0 + ro2 * rd1;
        const float R22 = ro1 * ro1 + ro2 * ro2 + rd2 * rd2 + 1e-6f;
        const float Rm[3][3] = {{R00, R10, R20}, {R10, R11, R21}, {R20, R21, R22}};

        // ---------- load state / control / measurement (small, direct) ----------
        const float2* xp2 = reinterpret_cast<const float2*>(x_prev + 6 * b);
        const float2 x01 = xp2[0], x23 = xp2[1], x45 = xp2[2];
        const float px = x01.x, py = x01.y, vx = x23.x, vy = x23.y;
        const float th = x45.x, om = x45.y;

        const float2 uu = *reinterpret_cast<const float2*>(u + 2 * b);
        const float mp  = fminf(fmaxf(uu.x, 0.0f), 1.0f);
        const float lat = uu.y;

        float s_th, c_th;
        __sincosf(th, &s_th, &c_th);

        // ---------- dynamics (x_pred) ----------
        const float Tm  = MAIN_THRUST * mp;
        const float ax  = -Tm * s_th;
        const float ay  =  Tm * c_th - GRAVITY;
        const float nvx = vx + ax * DT;
        const float nvy = vy + ay * DT;
        const float nom = om + lat * DT;          // SIDE_TORQUE = 1
        const float npx = px + nvx * DT;
        const float npy = py + nvy * DT;
        const float nth = th + nom * DT;
        const float xp[6] = {npx, npy, nvx, nvy, nth, nom};

        // ---------- Jacobian nonzeros ----------
        const float f24 = -Tm * c_th * DT;        // F[2][4]
        const float f34 = -Tm * s_th * DT;        // F[3][4]
        const float f04 = f24 * DT;               // F[0][4]
        const float f14 = f34 * DT;               // F[1][4]

        // ---------- read my P row from LDS (stride-37: conflict-free) ----------
        float P[36];
        const float* myrow = &smem[t * ROWPAD];
        #pragma unroll
        for (int j = 0; j < 36; ++j) P[j] = myrow[j];

        // ---------- P_pred = F P F^T + Q, in place ----------
        #pragma unroll
        for (int j = 0; j < 6; ++j) {
            P[0 * 6 + j] += DT * P[2 * 6 + j] + f04 * P[4 * 6 + j];
            P[1 * 6 + j] += DT * P[3 * 6 + j] + f14 * P[4 * 6 + j];
            P[2 * 6 + j] += f24 * P[4 * 6 + j];
            P[3 * 6 + j] += f34 * P[4 * 6 + j];
            P[4 * 6 + j] += DT * P[5 * 6 + j];
        }
        #pragma unroll
        for (int i = 0; i < 6; ++i) {
            const float m0 = P[i * 6 + 0], m1 = P[i * 6 + 1], m2 = P[i * 6 + 2];
            const float m3 = P[i * 6 + 3], m4 = P[i * 6 + 4], m5 = P[i * 6 + 5];
            P[i * 6 + 0] = m0 + DT * m2 + f04 * m4 + Q[i][0];
            P[i * 6 + 1] = m1 + DT * m3 + f14 * m4 + Q[i][1];
            P[i * 6 + 2] = m2 + f24 * m4 + Q[i][2];
            P[i * 6 + 3] = m3 + f34 * m4 + Q[i][3];
            P[i * 6 + 4] = m4 + DT * m5 + Q[i][4];
            P[i * 6 + 5] = m5 + Q[i][5];
        }

        // ---------- innovation ----------
        const float* zp = z + 3 * b;
        const float y0 = zp[0] - npx;
        const float y1 = zp[1] - npy;
        const float y2 = zp[2] - nth;

        // ---------- S = P_pred[h,h] + R, h = {0,1,4}; adjugate inverse ----------
        const float s00 = P[0 * 6 + 0] + Rm[0][0];
        const float s01 = P[0 * 6 + 1] + Rm[0][1];
        const float s02 = P[0 * 6 + 4] + Rm[0][2];
        const float s10 = P[1 * 6 + 0] + Rm[1][0];
        const float s11 = P[1 * 6 + 1] + Rm[1][1];
        const float s12 = P[1 * 6 + 4] + Rm[1][2];
        const float s20 = P[4 * 6 + 0] + Rm[2][0];
        const float s21 = P[4 * 6 + 1] + Rm[2][1];
        const float s22 = P[4 * 6 + 4] + Rm[2][2];

        const float det = s00 * (s11 * s22 - s12 * s21)
                        + s01 * (s12 * s20 - s10 * s22)
                        + s02 * (s10 * s21 - s11 * s20);
        const float invd = 1.0f / det;
        const float i00 = (s11 * s22 - s12 * s21) * invd;
        const float i01 = (s02 * s21 - s01 * s22) * invd;
        const float i02 = (s01 * s12 - s02 * s11) * invd;
        const float i10 = (s12 * s20 - s10 * s22) * invd;
        const float i11 = (s00 * s22 - s02 * s20) * invd;
        const float i12 = (s02 * s10 - s00 * s12) * invd;
        const float i20 = (s10 * s21 - s11 * s20) * invd;
        const float i21 = (s01 * s20 - s00 * s21) * invd;
        const float i22 = (s00 * s11 - s01 * s10) * invd;

        // ---------- K = HP^T S^{-1}  (6x3) ----------
        float K[6][3];
        #pragma unroll
        for (int i = 0; i < 6; ++i) {
            const float hp0 = P[0 * 6 + i];
            const float hp1 = P[1 * 6 + i];
            const float hp2 = P[4 * 6 + i];
            K[i][0] = i00 * hp0 + i01 * hp1 + i02 * hp2;
            K[i][1] = i10 * hp0 + i11 * hp1 + i12 * hp2;
            K[i][2] = i20 * hp0 + i21 * hp1 + i22 * hp2;
        }

        // ---------- x_upd = x_pred + K y; store (small, direct) ----------
        float2* xo2 = reinterpret_cast<float2*>(x_out + 6 * b);
        float xu[6];
        #pragma unroll
        for (int i = 0; i < 6; ++i)
            xu[i] = xp[i] + K[i][0] * y0 + K[i][1] * y1 + K[i][2] * y2;
        xo2[0] = make_float2(xu[0], xu[1]);
        xo2[1] = make_float2(xu[2], xu[3]);
        xo2[2] = make_float2(xu[4], xu[5]);

        // ---------- Joseph form: P_upd = IKH P_pred IKH^T + K R K^T ----------
        float r0[6], r1[6], r4[6];
        #pragma unroll
        for (int j = 0; j < 6; ++j) {
            r0[j] = P[0 * 6 + j];
            r1[j] = P[1 * 6 + j];
            r4[j] = P[4 * 6 + j];
        }
        #pragma unroll
        for (int i = 0; i < 6; ++i)
            #pragma unroll
            for (int j = 0; j < 6; ++j)
                P[i * 6 + j] -= K[i][0] * r0[j] + K[i][1] * r1[j] + K[i][2] * r4[j];

        float c0[6], c1[6], c4[6];
        #pragma unroll
        for (int i = 0; i < 6; ++i) {
            c0[i] = P[i * 6 + 0];
            c1[i] = P[i * 6 + 1];
            c4[i] = P[i * 6 + 4];
        }
        float KR[6][3];
        #pragma unroll
        for (int i = 0; i < 6; ++i) {
            #pragma unroll
            for (int a = 0; a < 3; ++a)
                KR[i][a] = K[i][0] * Rm[0][a] + K[i][1] * Rm[1][a] + K[i][2] * Rm[2][a];
        }
        #pragma unroll
        for (int i = 0; i < 6; ++i) {
            #pragma unroll
            for (int j = 0; j < 6; ++j) {
                P[i * 6 + j] += -(c0[i] * K[j][0] + c1[i] * K[j][1] + c4[i] * K[j][2])
                                + (KR[i][0] * K[j][0] + KR[i][1] * K[j][1] + KR[i][2] * K[j][2]);
            }
        }

        // ---------- my result row -> LDS (own row only; no barrier needed yet) ----------
        float* myrowW = &smem[t * ROWPAD];
        #pragma unroll
        for (int j = 0; j < 36; ++j) myrowW[j] = P[j];
    }
    __syncthreads();

    // ---------- phase 3: LDS -> coalesced global (P_out) ----------
    {
        float4* oP4 = reinterpret_cast<float4*>(P_out + blockElem0 * 36);
        #pragma unroll
        for (int k = 0; k < 9; ++k) {
            const int g4 = t + k * BLK;
            if (g4 < count4) {
                const int elem = g4 / 9;
                const int off4 = g4 % 9;
                const float* src = &smem[elem * ROWPAD + off4 * 4];
                float4 v;
                v.x = src[0]; v.y = src[1]; v.z = src[2]; v.w = src[3];
                oP4[g4] = v;
            }
        }
    }
}

extern "C" void kernel_launch(void* const* d_in, const int* in_sizes, int n_in,
                              void* d_out, int out_size, void* d_ws, size_t ws_size,
                              hipStream_t stream) {
    const float* z          = (const float*)d_in[0];
    const float* u          = (const float*)d_in[1];
    const float* x_prev     = (const float*)d_in[2];
    const float* P_prev     = (const float*)d_in[3];
    const float* q_log_diag = (const float*)d_in[4];
    const float* q_off_diag = (const float*)d_in[5];
    const float* r_log_diag = (const float*)d_in[6];
    const float* r_off_diag = (const float*)d_in[7];

    const int B = in_sizes[0] / 3;                 // z is (B,3)
    float* x_out = (float*)d_out;                  // (B,6)
    float* P_out = (float*)d_out + (size_t)B * 6;  // (B,36)

    const int grid = (B + BLK - 1) / BLK;
    ekf_kernel<<<grid, BLK, 0, stream>>>(z, u, x_prev, P_prev,
                                         q_log_diag, q_off_diag,
                                         r_log_diag, r_off_diag,
                                         x_out, P_out, B);
}

// Round 3
// 186.447 us; speedup vs baseline: 1.0516x; 1.0282x over previous
//
#include <hip/hip_runtime.h>

namespace {
constexpr float GRAVITY     = 10.0f;
constexpr float MAIN_THRUST = 6.0f;
constexpr float DT          = 0.02f;
constexpr int   BLK         = 128;
constexpr int   ROWPAD      = 44;   // 36 pad to 44 words: 16B-aligned rows, and
                                    // 44 ≡ 12 (mod 32) -> b128 row access is
                                    // bank-conflict-free (8 lanes cover 32 banks)
}

// Q (6x6) and R (3x3 packed lower: R00,R10,R11,R20,R21,R22) are batch-uniform.
// Compute once -> d_ws; main kernel s_loads them into SGPRs.
__global__ void qr_precompute(const float* __restrict__ qld,
                              const float* __restrict__ qod,
                              const float* __restrict__ rld,
                              const float* __restrict__ rod,
                              float* __restrict__ out)   // 42 floats
{
    if (threadIdx.x != 0 || blockIdx.x != 0) return;
    float L[6][6];
    for (int i = 0; i < 6; ++i)
        for (int j = 0; j < 6; ++j) L[i][j] = 0.0f;
    for (int i = 0; i < 6; ++i) L[i][i] = expf(qld[i]);
    L[1][0] = qod[0];
    L[2][0] = qod[1];  L[2][1] = qod[2];
    L[3][0] = qod[3];  L[3][1] = qod[4];  L[3][2] = qod[5];
    L[4][0] = qod[6];  L[4][1] = qod[7];  L[4][2] = qod[8];  L[4][3] = qod[9];
    L[5][0] = qod[10]; L[5][1] = qod[11]; L[5][2] = qod[12]; L[5][3] = qod[13];
    L[5][4] = qod[14];
    for (int i = 0; i < 6; ++i)
        for (int j = 0; j < 6; ++j) {
            float s = 0.0f;
            const int m = i < j ? i : j;
            for (int k = 0; k <= m; ++k) s += L[i][k] * L[j][k];
            if (i == j) s += 1e-6f;
            out[i * 6 + j] = s;
        }
    const float rd0 = expf(rld[0]), rd1 = expf(rld[1]), rd2 = expf(rld[2]);
    const float ro0 = rod[0], ro1 = rod[1], ro2 = rod[2];
    out[36] = rd0 * rd0 + 1e-6f;                          // R00
    out[37] = ro0 * rd0;                                  // R10
    out[38] = ro0 * ro0 + rd1 * rd1 + 1e-6f;              // R11
    out[39] = ro1 * rd0;                                  // R20
    out[40] = ro1 * ro0 + ro2 * rd1;                      // R21
    out[41] = ro1 * ro1 + ro2 * ro2 + rd2 * rd2 + 1e-6f;  // R22
}

// One thread per element; P staged through LDS (b128 both ways, conflict-free).
// Update uses the exact identity  IKH*P*IKH^T + K*R*K^T == P - K*(H P)
// (since K*S = HP^T when K = HP^T S^{-1}) -- saves ~380 FMA/thread vs Joseph.
__global__ __launch_bounds__(BLK) void ekf_kernel(
    const float* __restrict__ z,        // (B,3)
    const float* __restrict__ u,        // (B,2)
    const float* __restrict__ x_prev,   // (B,6)
    const float* __restrict__ P_prev,   // (B,36)
    const float* __restrict__ qr,       // (42,) uniform: Q[36], Rpacked[6]
    float* __restrict__ x_out,          // (B,6)
    float* __restrict__ P_out,          // (B,36)
    int B)
{
    __shared__ float smem[BLK * ROWPAD];   // 22528 B -> 7 blocks/CU

    const int t = threadIdx.x;
    const long long blockElem0 = (long long)blockIdx.x * BLK;
    const long long elemsLeft  = (long long)B - blockElem0;
    const int nElem  = elemsLeft >= BLK ? BLK : (int)elemsLeft;
    const int count4 = nElem * 9;

    // ---------- phase 1: coalesced global -> LDS (float4 both sides) ----------
    {
        const float4* gP4 = reinterpret_cast<const float4*>(P_prev + blockElem0 * 36);
        #pragma unroll
        for (int k = 0; k < 9; ++k) {
            const int g4 = t + k * BLK;
            if (g4 < count4) {
                const float4 v = gP4[g4];
                const int elem = g4 / 9;
                const int off4 = g4 % 9;
                *reinterpret_cast<float4*>(&smem[elem * ROWPAD + off4 * 4]) = v;
            }
        }
    }
    __syncthreads();

    const bool valid = (t < nElem);
    const long long b = blockElem0 + t;

    if (valid) {
        // ---------- uniform Q/R from d_ws (s_load -> SGPRs) ----------
        const float R00 = qr[36], R10 = qr[37], R11 = qr[38];
        const float R20 = qr[39], R21 = qr[40], R22 = qr[41];

        // ---------- state / control / measurement ----------
        const float2* xp2 = reinterpret_cast<const float2*>(x_prev + 6 * b);
        const float2 x01 = xp2[0], x23 = xp2[1], x45 = xp2[2];
        const float px = x01.x, py = x01.y, vx = x23.x, vy = x23.y;
        const float th = x45.x, om = x45.y;

        const float2 uu = *reinterpret_cast<const float2*>(u + 2 * b);
        const float mp  = fminf(fmaxf(uu.x, 0.0f), 1.0f);
        const float lat = uu.y;

        float s_th, c_th;
        __sincosf(th, &s_th, &c_th);

        // ---------- dynamics ----------
        const float Tm  = MAIN_THRUST * mp;
        const float ax  = -Tm * s_th;
        const float ay  =  Tm * c_th - GRAVITY;
        const float nvx = vx + ax * DT;
        const float nvy = vy + ay * DT;
        const float nom = om + lat * DT;          // SIDE_TORQUE = 1
        const float npx = px + nvx * DT;
        const float npy = py + nvy * DT;
        const float nth = th + nom * DT;
        const float xp[6] = {npx, npy, nvx, nvy, nth, nom};

        // ---------- Jacobian nonzeros ----------
        const float f24 = -Tm * c_th * DT;
        const float f34 = -Tm * s_th * DT;
        const float f04 = f24 * DT;
        const float f14 = f34 * DT;

        // ---------- my P row from LDS (9x ds_read_b128, conflict-free) ----------
        float P[36];
        const float* myrow = &smem[t * ROWPAD];
        #pragma unroll
        for (int k = 0; k < 9; ++k) {
            const float4 v = *reinterpret_cast<const float4*>(&myrow[k * 4]);
            P[4 * k + 0] = v.x; P[4 * k + 1] = v.y;
            P[4 * k + 2] = v.z; P[4 * k + 3] = v.w;
        }

        // ---------- P_pred = F P F^T + Q, in place ----------
        #pragma unroll
        for (int j = 0; j < 6; ++j) {
            P[0 * 6 + j] += DT * P[2 * 6 + j] + f04 * P[4 * 6 + j];
            P[1 * 6 + j] += DT * P[3 * 6 + j] + f14 * P[4 * 6 + j];
            P[2 * 6 + j] += f24 * P[4 * 6 + j];
            P[3 * 6 + j] += f34 * P[4 * 6 + j];
            P[4 * 6 + j] += DT * P[5 * 6 + j];
        }
        #pragma unroll
        for (int i = 0; i < 6; ++i) {
            const float m0 = P[i * 6 + 0], m1 = P[i * 6 + 1], m2 = P[i * 6 + 2];
            const float m3 = P[i * 6 + 3], m4 = P[i * 6 + 4], m5 = P[i * 6 + 5];
            P[i * 6 + 0] = m0 + DT * m2 + f04 * m4 + qr[i * 6 + 0];
            P[i * 6 + 1] = m1 + DT * m3 + f14 * m4 + qr[i * 6 + 1];
            P[i * 6 + 2] = m2 + f24 * m4 + qr[i * 6 + 2];
            P[i * 6 + 3] = m3 + f34 * m4 + qr[i * 6 + 3];
            P[i * 6 + 4] = m4 + DT * m5 + qr[i * 6 + 4];
            P[i * 6 + 5] = m5 + qr[i * 6 + 5];
        }

        // ---------- innovation ----------
        const float* zp = z + 3 * b;
        const float y0 = zp[0] - npx;
        const float y1 = zp[1] - npy;
        const float y2 = zp[2] - nth;

        // ---------- S = P[h,h] + R, h={0,1,4}; adjugate inverse ----------
        const float s00 = P[0 * 6 + 0] + R00;
        const float s01 = P[0 * 6 + 1] + R10;
        const float s02 = P[0 * 6 + 4] + R20;
        const float s10 = P[1 * 6 + 0] + R10;
        const float s11 = P[1 * 6 + 1] + R11;
        const float s12 = P[1 * 6 + 4] + R21;
        const float s20 = P[4 * 6 + 0] + R20;
        const float s21 = P[4 * 6 + 1] + R21;
        const float s22 = P[4 * 6 + 4] + R22;

        const float det = s00 * (s11 * s22 - s12 * s21)
                        + s01 * (s12 * s20 - s10 * s22)
                        + s02 * (s10 * s21 - s11 * s20);
        const float invd = 1.0f / det;
        const float i00 = (s11 * s22 - s12 * s21) * invd;
        const float i01 = (s02 * s21 - s01 * s22) * invd;
        const float i02 = (s01 * s12 - s02 * s11) * invd;
        const float i10 = (s12 * s20 - s10 * s22) * invd;
        const float i11 = (s00 * s22 - s02 * s20) * invd;
        const float i12 = (s02 * s10 - s00 * s12) * invd;
        const float i20 = (s10 * s21 - s11 * s20) * invd;
        const float i21 = (s01 * s20 - s00 * s21) * invd;
        const float i22 = (s00 * s11 - s01 * s10) * invd;

        // ---------- save HP rows (rows 0,1,4 of P_pred) ----------
        float r0[6], r1[6], r4[6];
        #pragma unroll
        for (int j = 0; j < 6; ++j) {
            r0[j] = P[0 * 6 + j];
            r1[j] = P[1 * 6 + j];
            r4[j] = P[4 * 6 + j];
        }

        // ---------- K = HP^T S^{-1} (6x3) ----------
        float K[6][3];
        #pragma unroll
        for (int i = 0; i < 6; ++i) {
            const float hp0 = r0[i], hp1 = r1[i], hp2 = r4[i];
            K[i][0] = i00 * hp0 + i01 * hp1 + i02 * hp2;
            K[i][1] = i10 * hp0 + i11 * hp1 + i12 * hp2;
            K[i][2] = i20 * hp0 + i21 * hp1 + i22 * hp2;
        }

        // ---------- x_upd = x_pred + K y (store direct; contiguous region) ----
        float2* xo2 = reinterpret_cast<float2*>(x_out + 6 * b);
        float xu[6];
        #pragma unroll
        for (int i = 0; i < 6; ++i)
            xu[i] = xp[i] + K[i][0] * y0 + K[i][1] * y1 + K[i][2] * y2;
        xo2[0] = make_float2(xu[0], xu[1]);
        xo2[1] = make_float2(xu[2], xu[3]);
        xo2[2] = make_float2(xu[4], xu[5]);

        // ---------- P_upd = P_pred - K * HP  (exact Joseph equivalent) --------
        #pragma unroll
        for (int i = 0; i < 6; ++i)
            #pragma unroll
            for (int j = 0; j < 6; ++j)
                P[i * 6 + j] -= K[i][0] * r0[j] + K[i][1] * r1[j] + K[i][2] * r4[j];

        // ---------- my row -> LDS (9x ds_write_b128) ----------
        float* myrowW = &smem[t * ROWPAD];
        #pragma unroll
        for (int k = 0; k < 9; ++k) {
            float4 v;
            v.x = P[4 * k + 0]; v.y = P[4 * k + 1];
            v.z = P[4 * k + 2]; v.w = P[4 * k + 3];
            *reinterpret_cast<float4*>(&myrowW[k * 4]) = v;
        }
    }
    __syncthreads();

    // ---------- phase 3: LDS -> coalesced global ----------
    {
        float4* oP4 = reinterpret_cast<float4*>(P_out + blockElem0 * 36);
        #pragma unroll
        for (int k = 0; k < 9; ++k) {
            const int g4 = t + k * BLK;
            if (g4 < count4) {
                const int elem = g4 / 9;
                const int off4 = g4 % 9;
                oP4[g4] = *reinterpret_cast<const float4*>(&smem[elem * ROWPAD + off4 * 4]);
            }
        }
    }
}

extern "C" void kernel_launch(void* const* d_in, const int* in_sizes, int n_in,
                              void* d_out, int out_size, void* d_ws, size_t ws_size,
                              hipStream_t stream) {
    const float* z          = (const float*)d_in[0];
    const float* u          = (const float*)d_in[1];
    const float* x_prev     = (const float*)d_in[2];
    const float* P_prev     = (const float*)d_in[3];
    const float* q_log_diag = (const float*)d_in[4];
    const float* q_off_diag = (const float*)d_in[5];
    const float* r_log_diag = (const float*)d_in[6];
    const float* r_off_diag = (const float*)d_in[7];

    const int B = in_sizes[0] / 3;                 // z is (B,3)
    float* x_out = (float*)d_out;                  // (B,6)
    float* P_out = (float*)d_out + (size_t)B * 6;  // (B,36)
    float* qrbuf = (float*)d_ws;                   // 42 floats

    qr_precompute<<<1, 64, 0, stream>>>(q_log_diag, q_off_diag,
                                        r_log_diag, r_off_diag, qrbuf);

    const int grid = (B + BLK - 1) / BLK;
    ekf_kernel<<<grid, BLK, 0, stream>>>(z, u, x_prev, P_prev, qrbuf,
                                         x_out, P_out, B);
}